// Round 8
// baseline (240.912 us; speedup 1.0000x reference)
//
#include <hip/hip_runtime.h>
#include <hip/hip_bf16.h>
#include <cstdint>

#define AXIS_CAP 32
#define GRID_SIZE_F 0.04f
#define BINS_PER_BATCH (AXIS_CAP * AXIS_CAP * AXIS_CAP)   // 32768
#define SCAN_TPB 256
#define BINS_PER_THREAD 4
#define BINS_PER_BLOCK (SCAN_TPB * BINS_PER_THREAD)       // 1024
#define KC_PPT 4                                           // keys_count pts/thread
#define RED_BLOCKS 2048                                    // persistent reduce grid

typedef float f32x4 __attribute__((ext_vector_type(4)));  // nontemporal-legal

__device__ __forceinline__ int point_batch(int i, const int* offs, int B) {
    int b = 0;
    for (int k = 0; k < B; ++k) b += (offs[k] <= i);
    return b;
}

// ---- init scratch ----
__global__ void init_kernel(uint32_t* binCount, int nbins, int* startBits, int B) {
    int i = blockIdx.x * blockDim.x + threadIdx.x;
    int stride = gridDim.x * blockDim.x;
    for (int v = i; v < nbins; v += stride) binCount[v] = 0;
    if (i < 3 * B) startBits[i] = 0x7F800000;  // +inf
}

// ---- per-batch min coord, hierarchical: reg -> wave shuffle -> LDS -> global ----
__global__ __launch_bounds__(256) void batch_min4_kernel(
        const float* __restrict__ coord, const int* __restrict__ offs,
        int B, int N, int* __restrict__ startBits) {
    __shared__ int smin[12];
    if (threadIdx.x < 12) smin[threadIdx.x] = 0x7F800000;
    __syncthreads();

    int o0 = offs[0];
    int o1 = (B > 1) ? offs[1] : o0;
    int o2 = (B > 2) ? offs[2] : o1;

    float m[4][3];
#pragma unroll
    for (int bb = 0; bb < 4; ++bb)
#pragma unroll
        for (int d = 0; d < 3; ++d) m[bb][d] = INFINITY;

    int gid = blockIdx.x * blockDim.x + threadIdx.x;
    int stride = gridDim.x * blockDim.x;
    for (int i = gid; i < N; i += stride) {
        float x = coord[(size_t)i * 3 + 0];
        float y = coord[(size_t)i * 3 + 1];
        float z = coord[(size_t)i * 3 + 2];
        int b = (i >= o0) + (i >= o1) + (i >= o2);
#pragma unroll
        for (int bb = 0; bb < 4; ++bb) {
            bool sel = (bb == b);
            m[bb][0] = fminf(m[bb][0], sel ? x : INFINITY);
            m[bb][1] = fminf(m[bb][1], sel ? y : INFINITY);
            m[bb][2] = fminf(m[bb][2], sel ? z : INFINITY);
        }
    }

#pragma unroll
    for (int bb = 0; bb < 4; ++bb)
#pragma unroll
        for (int d = 0; d < 3; ++d) {
            float v = m[bb][d];
            for (int off = 32; off > 0; off >>= 1)
                v = fminf(v, __shfl_xor(v, off));
            m[bb][d] = v;
        }

    if ((threadIdx.x & 63) == 0) {
#pragma unroll
        for (int bb = 0; bb < 4; ++bb)
#pragma unroll
            for (int d = 0; d < 3; ++d)
                atomicMin(&smin[bb * 3 + d], __float_as_int(m[bb][d]));
    }
    __syncthreads();
    if (threadIdx.x < 12 && (threadIdx.x / 3) < B)
        atomicMin(&startBits[threadIdx.x], smin[threadIdx.x]);
}

// ---- generic fallback for B > 4 ----
__global__ void batch_min_generic_kernel(const float* __restrict__ coord,
                                         const int* __restrict__ offs,
                                         int B, int N, int* startBits) {
    int i = blockIdx.x * blockDim.x + threadIdx.x;
    if (i >= N) return;
    int b = point_batch(i, offs, B);
    for (int d = 0; d < 3; ++d) {
        float c = coord[(size_t)i * 3 + d];
        atomicMin(&startBits[b * 3 + d], __float_as_int(c));
    }
}

// ---- per-point voxel key + histogram (B<=4 fast path) ----
__global__ __launch_bounds__(256) void keys_count4_kernel(
        const float* __restrict__ coord, const int* __restrict__ offs,
        const int* __restrict__ startBits, int B, int N,
        uint2* __restrict__ kr, uint32_t* __restrict__ binCount) {
    int o0 = offs[0];
    int o1 = (B > 1) ? offs[1] : o0;
    int o2 = (B > 2) ? offs[2] : o1;
    float s00 = __int_as_float(startBits[0]);
    float s01 = __int_as_float(startBits[1]);
    float s02 = __int_as_float(startBits[2]);
    float s10 = (B > 1) ? __int_as_float(startBits[3]) : 0.f;
    float s11 = (B > 1) ? __int_as_float(startBits[4]) : 0.f;
    float s12 = (B > 1) ? __int_as_float(startBits[5]) : 0.f;
    float s20 = (B > 2) ? __int_as_float(startBits[6]) : 0.f;
    float s21 = (B > 2) ? __int_as_float(startBits[7]) : 0.f;
    float s22 = (B > 2) ? __int_as_float(startBits[8]) : 0.f;
    float s30 = (B > 3) ? __int_as_float(startBits[9]) : 0.f;
    float s31 = (B > 3) ? __int_as_float(startBits[10]) : 0.f;
    float s32 = (B > 3) ? __int_as_float(startBits[11]) : 0.f;

    int i0 = blockIdx.x * (256 * KC_PPT) + threadIdx.x;
#pragma unroll
    for (int j = 0; j < KC_PPT; ++j) {
        int i = i0 + j * 256;
        if (i >= N) continue;
        float x = coord[(size_t)i * 3 + 0];
        float y = coord[(size_t)i * 3 + 1];
        float z = coord[(size_t)i * 3 + 2];
        int b = (i >= o0) + (i >= o1) + (i >= o2);
        float sx = (b == 0) ? s00 : (b == 1) ? s10 : (b == 2) ? s20 : s30;
        float sy = (b == 0) ? s01 : (b == 1) ? s11 : (b == 2) ? s21 : s31;
        float sz = (b == 0) ? s02 : (b == 1) ? s12 : (b == 2) ? s22 : s32;
        int vx = (int)floorf((x - sx) / GRID_SIZE_F);
        int vy = (int)floorf((y - sy) / GRID_SIZE_F);
        int vz = (int)floorf((z - sz) / GRID_SIZE_F);
        vx = vx < 0 ? 0 : (vx > AXIS_CAP - 1 ? AXIS_CAP - 1 : vx);
        vy = vy < 0 ? 0 : (vy > AXIS_CAP - 1 ? AXIS_CAP - 1 : vy);
        vz = vz < 0 ? 0 : (vz > AXIS_CAP - 1 ? AXIS_CAP - 1 : vz);
        uint32_t key = ((uint32_t)b * AXIS_CAP + vx) * AXIS_CAP * AXIS_CAP
                     + (uint32_t)vy * AXIS_CAP + vz;
        uint32_t r = atomicAdd(&binCount[key], 1u);
        kr[i] = make_uint2(key, r);
    }
}

// ---- generic keys_count for B > 4 ----
__global__ void keys_count_generic_kernel(
        const float* __restrict__ coord, const int* __restrict__ offs,
        const int* __restrict__ startBits, int B, int N,
        uint2* __restrict__ kr, uint32_t* __restrict__ binCount) {
    int i = blockIdx.x * blockDim.x + threadIdx.x;
    if (i >= N) return;
    int b = point_batch(i, offs, B);
    int v[3];
    for (int d = 0; d < 3; ++d) {
        float s = __int_as_float(startBits[b * 3 + d]);
        float q = (coord[(size_t)i * 3 + d] - s) / GRID_SIZE_F;
        int vi = (int)floorf(q);
        vi = vi < 0 ? 0 : (vi > AXIS_CAP - 1 ? AXIS_CAP - 1 : vi);
        v[d] = vi;
    }
    uint32_t key = ((uint32_t)b * AXIS_CAP + v[0]) * AXIS_CAP * AXIS_CAP
                 + (uint32_t)v[1] * AXIS_CAP + v[2];
    uint32_t r = atomicAdd(&binCount[key], 1u);
    kr[i] = make_uint2(key, r);
}

// ---- scan pass 1 ----
__global__ void scan1_kernel(const uint32_t* __restrict__ binCount,
                             uint32_t* __restrict__ binStart,
                             uint32_t* __restrict__ binSeg,
                             uint32_t* __restrict__ blockCnt,
                             uint32_t* __restrict__ blockOcc) {
    __shared__ uint32_t sC[SCAN_TPB], sO[SCAN_TPB];
    int t = threadIdx.x;
    int base = blockIdx.x * BINS_PER_BLOCK + t * BINS_PER_THREAD;
    uint32_t c[BINS_PER_THREAD];
    uint32_t tc = 0, to = 0;
#pragma unroll
    for (int j = 0; j < BINS_PER_THREAD; ++j) {
        c[j] = binCount[base + j];
        tc += c[j];
        to += (c[j] > 0u);
    }
    sC[t] = tc; sO[t] = to;
    __syncthreads();
    for (int off = 1; off < SCAN_TPB; off <<= 1) {
        uint32_t a = 0, b2 = 0;
        if (t >= off) { a = sC[t - off]; b2 = sO[t - off]; }
        __syncthreads();
        sC[t] += a; sO[t] += b2;
        __syncthreads();
    }
    uint32_t exC = sC[t] - tc;
    uint32_t exO = sO[t] - to;
#pragma unroll
    for (int j = 0; j < BINS_PER_THREAD; ++j) {
        binStart[base + j] = exC;
        binSeg[base + j] = exO;
        exC += c[j];
        exO += (c[j] > 0u);
    }
    if (t == SCAN_TPB - 1) {
        blockCnt[blockIdx.x] = sC[t];
        blockOcc[blockIdx.x] = sO[t];
    }
}

// ---- scan pass 2 ----
__global__ void scan2_kernel(uint32_t* blockCnt, uint32_t* blockOcc,
                             uint32_t* totals, int nb) {
    __shared__ uint32_t sC[SCAN_TPB], sO[SCAN_TPB];
    int t = threadIdx.x;
    uint32_t c = (t < nb) ? blockCnt[t] : 0u;
    uint32_t o = (t < nb) ? blockOcc[t] : 0u;
    sC[t] = c; sO[t] = o;
    __syncthreads();
    for (int off = 1; off < SCAN_TPB; off <<= 1) {
        uint32_t a = 0, b2 = 0;
        if (t >= off) { a = sC[t - off]; b2 = sO[t - off]; }
        __syncthreads();
        sC[t] += a; sO[t] += b2;
        __syncthreads();
    }
    if (t < nb) { blockCnt[t] = sC[t] - c; blockOcc[t] = sO[t] - o; }
    if (t == SCAN_TPB - 1) { totals[0] = sO[t]; totals[1] = sC[t]; }
}

// ---- scan pass 3 ----
__global__ void scan3_kernel(uint32_t* __restrict__ binStart,
                             uint32_t* __restrict__ binSeg,
                             const uint32_t* __restrict__ blockCnt,
                             const uint32_t* __restrict__ blockOcc) {
    int t = threadIdx.x;
    int base = blockIdx.x * BINS_PER_BLOCK + t * BINS_PER_THREAD;
    uint32_t oc = blockCnt[blockIdx.x];
    uint32_t oo = blockOcc[blockIdx.x];
#pragma unroll
    for (int j = 0; j < BINS_PER_THREAD; ++j) {
        binStart[base + j] += oc;
        binSeg[base + j] += oo;
    }
}

// ---- scatter: atomic-free; block 0 writes offset_out/n_vox tail ----
__global__ void scatter_kernel(const uint2* __restrict__ kr,
                               const uint32_t* __restrict__ binStart,
                               uint32_t* __restrict__ pointIdx, int N,
                               const uint32_t* __restrict__ binSeg,
                               const uint32_t* __restrict__ totals,
                               float* __restrict__ out, int B, int C) {
    int i = blockIdx.x * blockDim.x + threadIdx.x;
    if (blockIdx.x == 0 && threadIdx.x <= (unsigned)B) {
        uint32_t nvox = totals[0];
        float* tail = out + (size_t)N * 3 + (size_t)N * C;
        if (threadIdx.x < (unsigned)B) {
            uint32_t v = (threadIdx.x == (unsigned)(B - 1))
                             ? nvox
                             : binSeg[(size_t)(threadIdx.x + 1) * BINS_PER_BATCH];
            tail[threadIdx.x] = (float)v;
        }
        if (threadIdx.x == 0) tail[B] = (float)nvox;
    }
    if (i >= N) return;
    uint2 k = kr[i];
    pointIdx[binStart[k.x] + k.y] = (uint32_t)i;
}

// ---- persistent per-voxel reduction + grid-stride zero-padding ----
// 8192 waves total (all co-resident). Each wave owns bpw CONTIGUOUS bins:
// metadata for the run shares cache lines, pointIdx reads stream, feat_out
// writes stream. C==64 fast path: lane = channel, 16-deep unrolled gather
// (idempotent duplicate-row clamp at the tail). Pad loops are division-free
// 32-bit grid-stride.
__global__ __launch_bounds__(256) void reduce_kernel(
        const float* __restrict__ coord, const float* __restrict__ feat,
        const uint32_t* __restrict__ binCount,
        const uint32_t* __restrict__ binStart,
        const uint32_t* __restrict__ binSeg,
        const uint32_t* __restrict__ pointIdx,
        const uint32_t* __restrict__ totals,
        float* __restrict__ out, int N, int C, int NBINS, int bpw) {
    int wid = (blockIdx.x << 2) + (threadIdx.x >> 6);
    int lane = threadIdx.x & 63;
    float* feat_out = out + (size_t)N * 3;

    int b0 = wid * bpw;
    int b1 = min(b0 + bpw, NBINS);

    for (int bin = b0; bin < b1; ++bin) {
        uint32_t cnt = binCount[bin];
        if (cnt == 0u) continue;
        uint32_t st = binStart[bin];
        uint32_t seg = binSeg[bin];
        float sx = 0.f, sy = 0.f, sz = 0.f;

        if (C == 64) {
            float m = -INFINITY;
            for (uint32_t base = 0; base < cnt; base += 64) {
                uint32_t nchunk = min(64u, cnt - base);
                bool valid = lane < (int)nchunk;
                uint32_t myIdx = valid ? pointIdx[st + base + lane] : 0u;
                if (valid) {
                    const float* cp = coord + (size_t)myIdx * 3;
                    sx += cp[0]; sy += cp[1]; sz += cp[2];
                }
                for (uint32_t p = 0; p < nchunk; p += 16) {
                    float v[16];
#pragma unroll
                    for (int j = 0; j < 16; ++j) {
                        uint32_t pp = min(p + (uint32_t)j, nchunk - 1u);
                        uint32_t idx = __shfl(myIdx, (int)pp);
                        v[j] = feat[(size_t)idx * 64 + lane];
                    }
#pragma unroll
                    for (int s = 1; s < 16; s <<= 1)
#pragma unroll
                        for (int j = 0; j < 16; j += 2 * s)
                            v[j] = fmaxf(v[j], v[j + s]);
                    m = fmaxf(m, v[0]);
                }
            }
            feat_out[(size_t)seg * 64 + lane] = m;
        } else {
            for (uint32_t p = lane; p < cnt; p += 64) {
                uint32_t idx = pointIdx[st + p];
                sx += coord[(size_t)idx * 3 + 0];
                sy += coord[(size_t)idx * 3 + 1];
                sz += coord[(size_t)idx * 3 + 2];
            }
            for (int c = lane; c < C; c += 64) {
                float m = -INFINITY;
                for (uint32_t p = 0; p < cnt; ++p) {
                    uint32_t idx = pointIdx[st + p];
                    m = fmaxf(m, feat[(size_t)idx * C + c]);
                }
                feat_out[(size_t)seg * C + c] = m;
            }
        }

        for (int off = 32; off > 0; off >>= 1) {
            sx += __shfl_xor(sx, off);
            sy += __shfl_xor(sy, off);
            sz += __shfl_xor(sz, off);
        }
        if (lane == 0) {
            float inv = 1.0f / (float)cnt;
            out[(size_t)seg * 3 + 0] = sx * inv;
            out[(size_t)seg * 3 + 1] = sy * inv;
            out[(size_t)seg * 3 + 2] = sz * inv;
        }
    }

    // division-free grid-stride zero-pad of rows >= n_vox
    uint32_t nvox = totals[0];
    uint32_t tid = (uint32_t)blockIdx.x * blockDim.x + threadIdx.x;
    uint32_t nthreads = (uint32_t)gridDim.x * blockDim.x;
    uint32_t rows = (uint32_t)(N - (int)nvox);
    if ((C & 3) == 0) {
        f32x4 z4 = {0.f, 0.f, 0.f, 0.f};
        uint32_t quadsTotal = rows * (uint32_t)(C >> 2);
        f32x4* padBase = (f32x4*)(feat_out + (size_t)nvox * C);
        for (uint32_t q = tid; q < quadsTotal; q += nthreads)
            __builtin_nontemporal_store(z4, &padBase[q]);
    } else {
        uint32_t eTotal = rows * (uint32_t)C;
        float* padBase = feat_out + (size_t)nvox * C;
        for (uint32_t e = tid; e < eTotal; e += nthreads)
            __builtin_nontemporal_store(0.f, &padBase[e]);
    }
    {
        uint32_t cTotal = rows * 3u;
        float* cBase = out + (size_t)nvox * 3;
        for (uint32_t e = tid; e < cTotal; e += nthreads)
            __builtin_nontemporal_store(0.f, &cBase[e]);
    }
}

extern "C" void kernel_launch(void* const* d_in, const int* in_sizes, int n_in,
                              void* d_out, int out_size, void* d_ws, size_t ws_size,
                              hipStream_t stream) {
    const float* coord = (const float*)d_in[0];
    const float* feat  = (const float*)d_in[1];
    const int*   offs  = (const int*)d_in[2];
    float* out = (float*)d_out;

    int N = in_sizes[0] / 3;
    int C = in_sizes[1] / N;
    int B = in_sizes[2];
    int NBINS = B * BINS_PER_BATCH;          // 131072 for B=4
    int NB1 = NBINS / BINS_PER_BLOCK;        // 128

    // workspace layout
    uint8_t* w = (uint8_t*)d_ws;
    uint32_t* binCount = (uint32_t*)w;              w += (size_t)NBINS * 4;
    uint32_t* binStart = (uint32_t*)w;              w += (size_t)NBINS * 4;
    uint32_t* binSeg   = (uint32_t*)w;              w += (size_t)NBINS * 4;
    uint32_t* blockCnt = (uint32_t*)w;              w += (size_t)NB1 * 4;
    uint32_t* blockOcc = (uint32_t*)w;              w += (size_t)NB1 * 4;
    uint32_t* totals   = (uint32_t*)w;              w += 2 * 4;
    int*      startBits= (int*)w;                   w += (size_t)3 * B * 4 + 8;
    uint2*    kr       = (uint2*)w;                 w += (size_t)N * 8;
    uint32_t* pointIdx = (uint32_t*)w;              /* w += N*4 */

    int ptBlocks = (N + 255) / 256;
    int kcBlocks = (N + 256 * KC_PPT - 1) / (256 * KC_PPT);
    int nWaves = RED_BLOCKS * 4;
    int bpw = (NBINS + nWaves - 1) / nWaves;   // bins per wave (host-side)

    init_kernel<<<512, 256, 0, stream>>>(binCount, NBINS, startBits, B);
    if (B <= 4) {
        batch_min4_kernel<<<1024, 256, 0, stream>>>(coord, offs, B, N, startBits);
        keys_count4_kernel<<<kcBlocks, 256, 0, stream>>>(coord, offs, startBits,
                                                         B, N, kr, binCount);
    } else {
        batch_min_generic_kernel<<<ptBlocks, 256, 0, stream>>>(coord, offs, B, N,
                                                               startBits);
        keys_count_generic_kernel<<<ptBlocks, 256, 0, stream>>>(coord, offs,
                                                                startBits, B, N,
                                                                kr, binCount);
    }
    scan1_kernel<<<NB1, SCAN_TPB, 0, stream>>>(binCount, binStart, binSeg,
                                               blockCnt, blockOcc);
    scan2_kernel<<<1, SCAN_TPB, 0, stream>>>(blockCnt, blockOcc, totals, NB1);
    scan3_kernel<<<NB1, SCAN_TPB, 0, stream>>>(binStart, binSeg, blockCnt, blockOcc);
    scatter_kernel<<<ptBlocks, 256, 0, stream>>>(kr, binStart, pointIdx, N,
                                                 binSeg, totals, out, B, C);
    reduce_kernel<<<RED_BLOCKS, 256, 0, stream>>>(coord, feat, binCount, binStart,
                                                  binSeg, pointIdx, totals, out,
                                                  N, C, NBINS, bpw);
}

// Round 10
// 230.559 us; speedup vs baseline: 1.0449x; 1.0449x over previous
//
#include <hip/hip_runtime.h>
#include <hip/hip_bf16.h>
#include <cstdint>

#define AXIS_CAP 32
#define GRID_SIZE_F 0.04f
#define BINS_PER_BATCH (AXIS_CAP * AXIS_CAP * AXIS_CAP)   // 32768
#define SCAN_TPB 256
#define BINS_PER_THREAD 4
#define BINS_PER_BLOCK (SCAN_TPB * BINS_PER_THREAD)       // 1024
#define KC_PPT 4                                           // keys_count pts/thread

typedef float f32x4 __attribute__((ext_vector_type(4)));     // nontemporal-legal
typedef uint32_t u32x2 __attribute__((ext_vector_type(2)));  // nontemporal-legal

__device__ __forceinline__ int point_batch(int i, const int* offs, int B) {
    int b = 0;
    for (int k = 0; k < B; ++k) b += (offs[k] <= i);
    return b;
}

// ---- init scratch ----
__global__ void init_kernel(uint32_t* binCount, int nbins, int* startBits, int B) {
    int i = blockIdx.x * blockDim.x + threadIdx.x;
    int stride = gridDim.x * blockDim.x;
    for (int v = i; v < nbins; v += stride) binCount[v] = 0;
    if (i < 3 * B) startBits[i] = 0x7F800000;  // +inf
}

// ---- per-batch min coord, hierarchical: reg -> wave shuffle -> LDS -> global ----
__global__ __launch_bounds__(256) void batch_min4_kernel(
        const float* __restrict__ coord, const int* __restrict__ offs,
        int B, int N, int* __restrict__ startBits) {
    __shared__ int smin[12];
    if (threadIdx.x < 12) smin[threadIdx.x] = 0x7F800000;
    __syncthreads();

    int o0 = offs[0];
    int o1 = (B > 1) ? offs[1] : o0;
    int o2 = (B > 2) ? offs[2] : o1;

    float m[4][3];
#pragma unroll
    for (int bb = 0; bb < 4; ++bb)
#pragma unroll
        for (int d = 0; d < 3; ++d) m[bb][d] = INFINITY;

    int gid = blockIdx.x * blockDim.x + threadIdx.x;
    int stride = gridDim.x * blockDim.x;
    for (int i = gid; i < N; i += stride) {
        float x = coord[(size_t)i * 3 + 0];
        float y = coord[(size_t)i * 3 + 1];
        float z = coord[(size_t)i * 3 + 2];
        int b = (i >= o0) + (i >= o1) + (i >= o2);
#pragma unroll
        for (int bb = 0; bb < 4; ++bb) {
            bool sel = (bb == b);
            m[bb][0] = fminf(m[bb][0], sel ? x : INFINITY);
            m[bb][1] = fminf(m[bb][1], sel ? y : INFINITY);
            m[bb][2] = fminf(m[bb][2], sel ? z : INFINITY);
        }
    }

#pragma unroll
    for (int bb = 0; bb < 4; ++bb)
#pragma unroll
        for (int d = 0; d < 3; ++d) {
            float v = m[bb][d];
            for (int off = 32; off > 0; off >>= 1)
                v = fminf(v, __shfl_xor(v, off));
            m[bb][d] = v;
        }

    if ((threadIdx.x & 63) == 0) {
#pragma unroll
        for (int bb = 0; bb < 4; ++bb)
#pragma unroll
            for (int d = 0; d < 3; ++d)
                atomicMin(&smin[bb * 3 + d], __float_as_int(m[bb][d]));
    }
    __syncthreads();
    if (threadIdx.x < 12 && (threadIdx.x / 3) < B)
        atomicMin(&startBits[threadIdx.x], smin[threadIdx.x]);
}

// ---- generic fallback for B > 4 ----
__global__ void batch_min_generic_kernel(const float* __restrict__ coord,
                                         const int* __restrict__ offs,
                                         int B, int N, int* startBits) {
    int i = blockIdx.x * blockDim.x + threadIdx.x;
    if (i >= N) return;
    int b = point_batch(i, offs, B);
    for (int d = 0; d < 3; ++d) {
        float c = coord[(size_t)i * 3 + d];
        atomicMin(&startBits[b * 3 + d], __float_as_int(c));
    }
}

// ---- per-point voxel key + histogram (B<=4 fast path) ----
__global__ __launch_bounds__(256) void keys_count4_kernel(
        const float* __restrict__ coord, const int* __restrict__ offs,
        const int* __restrict__ startBits, int B, int N,
        u32x2* __restrict__ kr, uint32_t* __restrict__ binCount) {
    int o0 = offs[0];
    int o1 = (B > 1) ? offs[1] : o0;
    int o2 = (B > 2) ? offs[2] : o1;
    float s00 = __int_as_float(startBits[0]);
    float s01 = __int_as_float(startBits[1]);
    float s02 = __int_as_float(startBits[2]);
    float s10 = (B > 1) ? __int_as_float(startBits[3]) : 0.f;
    float s11 = (B > 1) ? __int_as_float(startBits[4]) : 0.f;
    float s12 = (B > 1) ? __int_as_float(startBits[5]) : 0.f;
    float s20 = (B > 2) ? __int_as_float(startBits[6]) : 0.f;
    float s21 = (B > 2) ? __int_as_float(startBits[7]) : 0.f;
    float s22 = (B > 2) ? __int_as_float(startBits[8]) : 0.f;
    float s30 = (B > 3) ? __int_as_float(startBits[9]) : 0.f;
    float s31 = (B > 3) ? __int_as_float(startBits[10]) : 0.f;
    float s32 = (B > 3) ? __int_as_float(startBits[11]) : 0.f;

    int i0 = blockIdx.x * (256 * KC_PPT) + threadIdx.x;
#pragma unroll
    for (int j = 0; j < KC_PPT; ++j) {
        int i = i0 + j * 256;
        if (i >= N) continue;
        float x = coord[(size_t)i * 3 + 0];
        float y = coord[(size_t)i * 3 + 1];
        float z = coord[(size_t)i * 3 + 2];
        int b = (i >= o0) + (i >= o1) + (i >= o2);
        float sx = (b == 0) ? s00 : (b == 1) ? s10 : (b == 2) ? s20 : s30;
        float sy = (b == 0) ? s01 : (b == 1) ? s11 : (b == 2) ? s21 : s31;
        float sz = (b == 0) ? s02 : (b == 1) ? s12 : (b == 2) ? s22 : s32;
        int vx = (int)floorf((x - sx) / GRID_SIZE_F);
        int vy = (int)floorf((y - sy) / GRID_SIZE_F);
        int vz = (int)floorf((z - sz) / GRID_SIZE_F);
        vx = vx < 0 ? 0 : (vx > AXIS_CAP - 1 ? AXIS_CAP - 1 : vx);
        vy = vy < 0 ? 0 : (vy > AXIS_CAP - 1 ? AXIS_CAP - 1 : vy);
        vz = vz < 0 ? 0 : (vz > AXIS_CAP - 1 ? AXIS_CAP - 1 : vz);
        uint32_t key = ((uint32_t)b * AXIS_CAP + vx) * AXIS_CAP * AXIS_CAP
                     + (uint32_t)vy * AXIS_CAP + vz;
        uint32_t r = atomicAdd(&binCount[key], 1u);
        u32x2 kv = {key, r};
        kr[i] = kv;
    }
}

// ---- generic keys_count for B > 4 ----
__global__ void keys_count_generic_kernel(
        const float* __restrict__ coord, const int* __restrict__ offs,
        const int* __restrict__ startBits, int B, int N,
        u32x2* __restrict__ kr, uint32_t* __restrict__ binCount) {
    int i = blockIdx.x * blockDim.x + threadIdx.x;
    if (i >= N) return;
    int b = point_batch(i, offs, B);
    int v[3];
    for (int d = 0; d < 3; ++d) {
        float s = __int_as_float(startBits[b * 3 + d]);
        float q = (coord[(size_t)i * 3 + d] - s) / GRID_SIZE_F;
        int vi = (int)floorf(q);
        vi = vi < 0 ? 0 : (vi > AXIS_CAP - 1 ? AXIS_CAP - 1 : vi);
        v[d] = vi;
    }
    uint32_t key = ((uint32_t)b * AXIS_CAP + v[0]) * AXIS_CAP * AXIS_CAP
                 + (uint32_t)v[1] * AXIS_CAP + v[2];
    uint32_t r = atomicAdd(&binCount[key], 1u);
    u32x2 kv = {key, r};
    kr[i] = kv;
}

// ---- scan pass 1 ----
__global__ void scan1_kernel(const uint32_t* __restrict__ binCount,
                             uint32_t* __restrict__ binStart,
                             uint32_t* __restrict__ binSeg,
                             uint32_t* __restrict__ blockCnt,
                             uint32_t* __restrict__ blockOcc) {
    __shared__ uint32_t sC[SCAN_TPB], sO[SCAN_TPB];
    int t = threadIdx.x;
    int base = blockIdx.x * BINS_PER_BLOCK + t * BINS_PER_THREAD;
    uint32_t c[BINS_PER_THREAD];
    uint32_t tc = 0, to = 0;
#pragma unroll
    for (int j = 0; j < BINS_PER_THREAD; ++j) {
        c[j] = binCount[base + j];
        tc += c[j];
        to += (c[j] > 0u);
    }
    sC[t] = tc; sO[t] = to;
    __syncthreads();
    for (int off = 1; off < SCAN_TPB; off <<= 1) {
        uint32_t a = 0, b2 = 0;
        if (t >= off) { a = sC[t - off]; b2 = sO[t - off]; }
        __syncthreads();
        sC[t] += a; sO[t] += b2;
        __syncthreads();
    }
    uint32_t exC = sC[t] - tc;
    uint32_t exO = sO[t] - to;
#pragma unroll
    for (int j = 0; j < BINS_PER_THREAD; ++j) {
        binStart[base + j] = exC;
        binSeg[base + j] = exO;
        exC += c[j];
        exO += (c[j] > 0u);
    }
    if (t == SCAN_TPB - 1) {
        blockCnt[blockIdx.x] = sC[t];
        blockOcc[blockIdx.x] = sO[t];
    }
}

// ---- scan pass 2 ----
__global__ void scan2_kernel(uint32_t* blockCnt, uint32_t* blockOcc,
                             uint32_t* totals, int nb) {
    __shared__ uint32_t sC[SCAN_TPB], sO[SCAN_TPB];
    int t = threadIdx.x;
    uint32_t c = (t < nb) ? blockCnt[t] : 0u;
    uint32_t o = (t < nb) ? blockOcc[t] : 0u;
    sC[t] = c; sO[t] = o;
    __syncthreads();
    for (int off = 1; off < SCAN_TPB; off <<= 1) {
        uint32_t a = 0, b2 = 0;
        if (t >= off) { a = sC[t - off]; b2 = sO[t - off]; }
        __syncthreads();
        sC[t] += a; sO[t] += b2;
        __syncthreads();
    }
    if (t < nb) { blockCnt[t] = sC[t] - c; blockOcc[t] = sO[t] - o; }
    if (t == SCAN_TPB - 1) { totals[0] = sO[t]; totals[1] = sC[t]; }
}

// ---- scan pass 3 ----
__global__ void scan3_kernel(uint32_t* __restrict__ binStart,
                             uint32_t* __restrict__ binSeg,
                             const uint32_t* __restrict__ blockCnt,
                             const uint32_t* __restrict__ blockOcc) {
    int t = threadIdx.x;
    int base = blockIdx.x * BINS_PER_BLOCK + t * BINS_PER_THREAD;
    uint32_t oc = blockCnt[blockIdx.x];
    uint32_t oo = blockOcc[blockIdx.x];
#pragma unroll
    for (int j = 0; j < BINS_PER_THREAD; ++j) {
        binStart[base + j] += oc;
        binSeg[base + j] += oo;
    }
}

// ---- scatter: atomic-free; block 0 writes offset_out/n_vox tail ----
__global__ void scatter_kernel(const u32x2* __restrict__ kr,
                               const uint32_t* __restrict__ binStart,
                               uint32_t* __restrict__ pointIdx, int N,
                               const uint32_t* __restrict__ binSeg,
                               const uint32_t* __restrict__ totals,
                               float* __restrict__ out, int B, int C) {
    int i = blockIdx.x * blockDim.x + threadIdx.x;
    if (blockIdx.x == 0 && threadIdx.x <= (unsigned)B) {
        uint32_t nvox = totals[0];
        float* tail = out + (size_t)N * 3 + (size_t)N * C;
        if (threadIdx.x < (unsigned)B) {
            uint32_t v = (threadIdx.x == (unsigned)(B - 1))
                             ? nvox
                             : binSeg[(size_t)(threadIdx.x + 1) * BINS_PER_BATCH];
            tail[threadIdx.x] = (float)v;
        }
        if (threadIdx.x == 0) tail[B] = (float)nvox;
    }
    if (i >= N) return;
    u32x2 k = __builtin_nontemporal_load(&kr[i]);
    pointIdx[binStart[k.x] + k.y] = (uint32_t)i;
}

// ---- per-voxel reduction (gather only; pad is a separate kernel) ----
// One wave per bin, 4 waves per block. C==64 fast path: lane = channel,
// 16-deep unrolled row gather (idempotent duplicate-row clamp at the tail),
// nontemporal loads on read-once streams (feat rows, pointIdx) so the random
// gather doesn't thrash L3 (coord stays cached: ~10 reuses per line).
__global__ __launch_bounds__(256) void reduce_kernel(
        const float* __restrict__ coord, const float* __restrict__ feat,
        const uint32_t* __restrict__ binCount,
        const uint32_t* __restrict__ binStart,
        const uint32_t* __restrict__ binSeg,
        const uint32_t* __restrict__ pointIdx,
        float* __restrict__ out, int N, int C) {
    int wid = (blockIdx.x << 2) + (threadIdx.x >> 6);   // global wave id = bin
    int lane = threadIdx.x & 63;
    uint32_t cnt = binCount[wid];
    if (cnt == 0u) return;
    float* feat_out = out + (size_t)N * 3;

    uint32_t st = binStart[wid];
    uint32_t seg = binSeg[wid];
    float sx = 0.f, sy = 0.f, sz = 0.f;

    if (C == 64) {
        float m = -INFINITY;
        for (uint32_t base = 0; base < cnt; base += 64) {
            uint32_t nchunk = min(64u, cnt - base);
            bool valid = lane < (int)nchunk;
            uint32_t myIdx =
                valid ? __builtin_nontemporal_load(&pointIdx[st + base + lane])
                      : 0u;
            if (valid) {
                const float* cp = coord + (size_t)myIdx * 3;
                sx += cp[0]; sy += cp[1]; sz += cp[2];
            }
            for (uint32_t p = 0; p < nchunk; p += 16) {
                float v[16];
#pragma unroll
                for (int j = 0; j < 16; ++j) {
                    uint32_t pp = min(p + (uint32_t)j, nchunk - 1u);
                    uint32_t idx = __shfl(myIdx, (int)pp);
                    v[j] = __builtin_nontemporal_load(
                        &feat[(size_t)idx * 64 + lane]);
                }
#pragma unroll
                for (int s = 1; s < 16; s <<= 1)
#pragma unroll
                    for (int j = 0; j < 16; j += 2 * s)
                        v[j] = fmaxf(v[j], v[j + s]);
                m = fmaxf(m, v[0]);
            }
        }
        __builtin_nontemporal_store(m, &feat_out[(size_t)seg * 64 + lane]);
    } else {
        for (uint32_t p = lane; p < cnt; p += 64) {
            uint32_t idx = pointIdx[st + p];
            sx += coord[(size_t)idx * 3 + 0];
            sy += coord[(size_t)idx * 3 + 1];
            sz += coord[(size_t)idx * 3 + 2];
        }
        for (int c = lane; c < C; c += 64) {
            float m = -INFINITY;
            for (uint32_t p = 0; p < cnt; ++p) {
                uint32_t idx = pointIdx[st + p];
                m = fmaxf(m, feat[(size_t)idx * C + c]);
            }
            feat_out[(size_t)seg * C + c] = m;
        }
    }

    for (int off = 32; off > 0; off >>= 1) {
        sx += __shfl_xor(sx, off);
        sy += __shfl_xor(sy, off);
        sz += __shfl_xor(sz, off);
    }
    if (lane == 0) {
        float inv = 1.0f / (float)cnt;
        out[(size_t)seg * 3 + 0] = sx * inv;
        out[(size_t)seg * 3 + 1] = sy * inv;
        out[(size_t)seg * 3 + 2] = sz * inv;
    }
}

// ---- zero padding rows >= n_vox (pure NT streaming store kernel) ----
__global__ __launch_bounds__(256) void pad_kernel(
        float* __restrict__ out, const uint32_t* __restrict__ totals,
        int N, int C) {
    uint32_t nvox = totals[0];
    uint32_t tid = (uint32_t)blockIdx.x * blockDim.x + threadIdx.x;
    uint32_t nthreads = (uint32_t)gridDim.x * blockDim.x;
    uint32_t rows = (uint32_t)N - nvox;
    float* featBase = out + (size_t)N * 3;
    if ((C & 3) == 0) {
        f32x4 z4 = {0.f, 0.f, 0.f, 0.f};
        uint32_t quadsTotal = rows * (uint32_t)(C >> 2);
        f32x4* padBase = (f32x4*)(featBase + (size_t)nvox * C);
        for (uint32_t q = tid; q < quadsTotal; q += nthreads)
            __builtin_nontemporal_store(z4, &padBase[q]);
    } else {
        uint32_t eTotal = rows * (uint32_t)C;
        float* padBase = featBase + (size_t)nvox * C;
        for (uint32_t e = tid; e < eTotal; e += nthreads)
            __builtin_nontemporal_store(0.f, &padBase[e]);
    }
    {
        uint32_t cTotal = rows * 3u;
        float* cBase = out + (size_t)nvox * 3;
        for (uint32_t e = tid; e < cTotal; e += nthreads)
            __builtin_nontemporal_store(0.f, &cBase[e]);
    }
}

extern "C" void kernel_launch(void* const* d_in, const int* in_sizes, int n_in,
                              void* d_out, int out_size, void* d_ws, size_t ws_size,
                              hipStream_t stream) {
    const float* coord = (const float*)d_in[0];
    const float* feat  = (const float*)d_in[1];
    const int*   offs  = (const int*)d_in[2];
    float* out = (float*)d_out;

    int N = in_sizes[0] / 3;
    int C = in_sizes[1] / N;
    int B = in_sizes[2];
    int NBINS = B * BINS_PER_BATCH;          // 131072 for B=4
    int NB1 = NBINS / BINS_PER_BLOCK;        // 128

    // workspace layout
    uint8_t* w = (uint8_t*)d_ws;
    uint32_t* binCount = (uint32_t*)w;              w += (size_t)NBINS * 4;
    uint32_t* binStart = (uint32_t*)w;              w += (size_t)NBINS * 4;
    uint32_t* binSeg   = (uint32_t*)w;              w += (size_t)NBINS * 4;
    uint32_t* blockCnt = (uint32_t*)w;              w += (size_t)NB1 * 4;
    uint32_t* blockOcc = (uint32_t*)w;              w += (size_t)NB1 * 4;
    uint32_t* totals   = (uint32_t*)w;              w += 2 * 4;
    int*      startBits= (int*)w;                   w += (size_t)3 * B * 4 + 8;
    u32x2*    kr       = (u32x2*)w;                 w += (size_t)N * 8;
    uint32_t* pointIdx = (uint32_t*)w;              /* w += N*4 */

    int ptBlocks = (N + 255) / 256;
    int kcBlocks = (N + 256 * KC_PPT - 1) / (256 * KC_PPT);

    init_kernel<<<512, 256, 0, stream>>>(binCount, NBINS, startBits, B);
    if (B <= 4) {
        batch_min4_kernel<<<1024, 256, 0, stream>>>(coord, offs, B, N, startBits);
        keys_count4_kernel<<<kcBlocks, 256, 0, stream>>>(coord, offs, startBits,
                                                         B, N, kr, binCount);
    } else {
        batch_min_generic_kernel<<<ptBlocks, 256, 0, stream>>>(coord, offs, B, N,
                                                               startBits);
        keys_count_generic_kernel<<<ptBlocks, 256, 0, stream>>>(coord, offs,
                                                                startBits, B, N,
                                                                kr, binCount);
    }
    scan1_kernel<<<NB1, SCAN_TPB, 0, stream>>>(binCount, binStart, binSeg,
                                               blockCnt, blockOcc);
    scan2_kernel<<<1, SCAN_TPB, 0, stream>>>(blockCnt, blockOcc, totals, NB1);
    scan3_kernel<<<NB1, SCAN_TPB, 0, stream>>>(binStart, binSeg, blockCnt, blockOcc);
    scatter_kernel<<<ptBlocks, 256, 0, stream>>>(kr, binStart, pointIdx, N,
                                                 binSeg, totals, out, B, C);
    reduce_kernel<<<NBINS / 4, 256, 0, stream>>>(coord, feat, binCount, binStart,
                                                 binSeg, pointIdx, out, N, C);
    pad_kernel<<<2048, 256, 0, stream>>>(out, totals, N, C);
}

// Round 11
// 188.534 us; speedup vs baseline: 1.2778x; 1.2229x over previous
//
#include <hip/hip_runtime.h>
#include <hip/hip_bf16.h>
#include <cstdint>

#define AXIS_CAP 32
#define GRID_SIZE_F 0.04f
#define BINS_PER_BATCH (AXIS_CAP * AXIS_CAP * AXIS_CAP)   // 32768
#define SCAN_TPB 256
#define BINS_PER_THREAD 4
#define BINS_PER_BLOCK (SCAN_TPB * BINS_PER_THREAD)       // 1024
#define KC_PPT 4                                           // keys_count pts/thread

typedef float f32x4 __attribute__((ext_vector_type(4)));     // nontemporal-legal
typedef uint32_t u32x2 __attribute__((ext_vector_type(2)));  // nontemporal-legal

__device__ __forceinline__ int point_batch(int i, const int* offs, int B) {
    int b = 0;
    for (int k = 0; k < B; ++k) b += (offs[k] <= i);
    return b;
}

// ---- init scratch ----
__global__ void init_kernel(uint32_t* binCount, int nbins, int* startBits, int B) {
    int i = blockIdx.x * blockDim.x + threadIdx.x;
    int stride = gridDim.x * blockDim.x;
    for (int v = i; v < nbins; v += stride) binCount[v] = 0;
    if (i < 3 * B) startBits[i] = 0x7F800000;  // +inf
}

// ---- per-batch min coord, hierarchical: reg -> wave shuffle -> LDS -> global ----
__global__ __launch_bounds__(256) void batch_min4_kernel(
        const float* __restrict__ coord, const int* __restrict__ offs,
        int B, int N, int* __restrict__ startBits) {
    __shared__ int smin[12];
    if (threadIdx.x < 12) smin[threadIdx.x] = 0x7F800000;
    __syncthreads();

    int o0 = offs[0];
    int o1 = (B > 1) ? offs[1] : o0;
    int o2 = (B > 2) ? offs[2] : o1;

    float m[4][3];
#pragma unroll
    for (int bb = 0; bb < 4; ++bb)
#pragma unroll
        for (int d = 0; d < 3; ++d) m[bb][d] = INFINITY;

    int gid = blockIdx.x * blockDim.x + threadIdx.x;
    int stride = gridDim.x * blockDim.x;
    for (int i = gid; i < N; i += stride) {
        float x = coord[(size_t)i * 3 + 0];
        float y = coord[(size_t)i * 3 + 1];
        float z = coord[(size_t)i * 3 + 2];
        int b = (i >= o0) + (i >= o1) + (i >= o2);
#pragma unroll
        for (int bb = 0; bb < 4; ++bb) {
            bool sel = (bb == b);
            m[bb][0] = fminf(m[bb][0], sel ? x : INFINITY);
            m[bb][1] = fminf(m[bb][1], sel ? y : INFINITY);
            m[bb][2] = fminf(m[bb][2], sel ? z : INFINITY);
        }
    }

#pragma unroll
    for (int bb = 0; bb < 4; ++bb)
#pragma unroll
        for (int d = 0; d < 3; ++d) {
            float v = m[bb][d];
            for (int off = 32; off > 0; off >>= 1)
                v = fminf(v, __shfl_xor(v, off));
            m[bb][d] = v;
        }

    if ((threadIdx.x & 63) == 0) {
#pragma unroll
        for (int bb = 0; bb < 4; ++bb)
#pragma unroll
            for (int d = 0; d < 3; ++d)
                atomicMin(&smin[bb * 3 + d], __float_as_int(m[bb][d]));
    }
    __syncthreads();
    if (threadIdx.x < 12 && (threadIdx.x / 3) < B)
        atomicMin(&startBits[threadIdx.x], smin[threadIdx.x]);
}

// ---- generic fallback for B > 4 ----
__global__ void batch_min_generic_kernel(const float* __restrict__ coord,
                                         const int* __restrict__ offs,
                                         int B, int N, int* startBits) {
    int i = blockIdx.x * blockDim.x + threadIdx.x;
    if (i >= N) return;
    int b = point_batch(i, offs, B);
    for (int d = 0; d < 3; ++d) {
        float c = coord[(size_t)i * 3 + d];
        atomicMin(&startBits[b * 3 + d], __float_as_int(c));
    }
}

// ---- per-point voxel key + histogram (B<=4 fast path) ----
__global__ __launch_bounds__(256) void keys_count4_kernel(
        const float* __restrict__ coord, const int* __restrict__ offs,
        const int* __restrict__ startBits, int B, int N,
        u32x2* __restrict__ kr, uint32_t* __restrict__ binCount) {
    int o0 = offs[0];
    int o1 = (B > 1) ? offs[1] : o0;
    int o2 = (B > 2) ? offs[2] : o1;
    float s00 = __int_as_float(startBits[0]);
    float s01 = __int_as_float(startBits[1]);
    float s02 = __int_as_float(startBits[2]);
    float s10 = (B > 1) ? __int_as_float(startBits[3]) : 0.f;
    float s11 = (B > 1) ? __int_as_float(startBits[4]) : 0.f;
    float s12 = (B > 1) ? __int_as_float(startBits[5]) : 0.f;
    float s20 = (B > 2) ? __int_as_float(startBits[6]) : 0.f;
    float s21 = (B > 2) ? __int_as_float(startBits[7]) : 0.f;
    float s22 = (B > 2) ? __int_as_float(startBits[8]) : 0.f;
    float s30 = (B > 3) ? __int_as_float(startBits[9]) : 0.f;
    float s31 = (B > 3) ? __int_as_float(startBits[10]) : 0.f;
    float s32 = (B > 3) ? __int_as_float(startBits[11]) : 0.f;

    int i0 = blockIdx.x * (256 * KC_PPT) + threadIdx.x;
#pragma unroll
    for (int j = 0; j < KC_PPT; ++j) {
        int i = i0 + j * 256;
        if (i >= N) continue;
        float x = coord[(size_t)i * 3 + 0];
        float y = coord[(size_t)i * 3 + 1];
        float z = coord[(size_t)i * 3 + 2];
        int b = (i >= o0) + (i >= o1) + (i >= o2);
        float sx = (b == 0) ? s00 : (b == 1) ? s10 : (b == 2) ? s20 : s30;
        float sy = (b == 0) ? s01 : (b == 1) ? s11 : (b == 2) ? s21 : s31;
        float sz = (b == 0) ? s02 : (b == 1) ? s12 : (b == 2) ? s22 : s32;
        int vx = (int)floorf((x - sx) / GRID_SIZE_F);
        int vy = (int)floorf((y - sy) / GRID_SIZE_F);
        int vz = (int)floorf((z - sz) / GRID_SIZE_F);
        vx = vx < 0 ? 0 : (vx > AXIS_CAP - 1 ? AXIS_CAP - 1 : vx);
        vy = vy < 0 ? 0 : (vy > AXIS_CAP - 1 ? AXIS_CAP - 1 : vy);
        vz = vz < 0 ? 0 : (vz > AXIS_CAP - 1 ? AXIS_CAP - 1 : vz);
        uint32_t key = ((uint32_t)b * AXIS_CAP + vx) * AXIS_CAP * AXIS_CAP
                     + (uint32_t)vy * AXIS_CAP + vz;
        uint32_t r = atomicAdd(&binCount[key], 1u);
        u32x2 kv = {key, r};
        kr[i] = kv;
    }
}

// ---- generic keys_count for B > 4 ----
__global__ void keys_count_generic_kernel(
        const float* __restrict__ coord, const int* __restrict__ offs,
        const int* __restrict__ startBits, int B, int N,
        u32x2* __restrict__ kr, uint32_t* __restrict__ binCount) {
    int i = blockIdx.x * blockDim.x + threadIdx.x;
    if (i >= N) return;
    int b = point_batch(i, offs, B);
    int v[3];
    for (int d = 0; d < 3; ++d) {
        float s = __int_as_float(startBits[b * 3 + d]);
        float q = (coord[(size_t)i * 3 + d] - s) / GRID_SIZE_F;
        int vi = (int)floorf(q);
        vi = vi < 0 ? 0 : (vi > AXIS_CAP - 1 ? AXIS_CAP - 1 : vi);
        v[d] = vi;
    }
    uint32_t key = ((uint32_t)b * AXIS_CAP + v[0]) * AXIS_CAP * AXIS_CAP
                 + (uint32_t)v[1] * AXIS_CAP + v[2];
    uint32_t r = atomicAdd(&binCount[key], 1u);
    u32x2 kv = {key, r};
    kr[i] = kv;
}

// ---- scan pass 1 ----
__global__ void scan1_kernel(const uint32_t* __restrict__ binCount,
                             uint32_t* __restrict__ binStart,
                             uint32_t* __restrict__ binSeg,
                             uint32_t* __restrict__ blockCnt,
                             uint32_t* __restrict__ blockOcc) {
    __shared__ uint32_t sC[SCAN_TPB], sO[SCAN_TPB];
    int t = threadIdx.x;
    int base = blockIdx.x * BINS_PER_BLOCK + t * BINS_PER_THREAD;
    uint32_t c[BINS_PER_THREAD];
    uint32_t tc = 0, to = 0;
#pragma unroll
    for (int j = 0; j < BINS_PER_THREAD; ++j) {
        c[j] = binCount[base + j];
        tc += c[j];
        to += (c[j] > 0u);
    }
    sC[t] = tc; sO[t] = to;
    __syncthreads();
    for (int off = 1; off < SCAN_TPB; off <<= 1) {
        uint32_t a = 0, b2 = 0;
        if (t >= off) { a = sC[t - off]; b2 = sO[t - off]; }
        __syncthreads();
        sC[t] += a; sO[t] += b2;
        __syncthreads();
    }
    uint32_t exC = sC[t] - tc;
    uint32_t exO = sO[t] - to;
#pragma unroll
    for (int j = 0; j < BINS_PER_THREAD; ++j) {
        binStart[base + j] = exC;
        binSeg[base + j] = exO;
        exC += c[j];
        exO += (c[j] > 0u);
    }
    if (t == SCAN_TPB - 1) {
        blockCnt[blockIdx.x] = sC[t];
        blockOcc[blockIdx.x] = sO[t];
    }
}

// ---- scan pass 2 ----
__global__ void scan2_kernel(uint32_t* blockCnt, uint32_t* blockOcc,
                             uint32_t* totals, int nb) {
    __shared__ uint32_t sC[SCAN_TPB], sO[SCAN_TPB];
    int t = threadIdx.x;
    uint32_t c = (t < nb) ? blockCnt[t] : 0u;
    uint32_t o = (t < nb) ? blockOcc[t] : 0u;
    sC[t] = c; sO[t] = o;
    __syncthreads();
    for (int off = 1; off < SCAN_TPB; off <<= 1) {
        uint32_t a = 0, b2 = 0;
        if (t >= off) { a = sC[t - off]; b2 = sO[t - off]; }
        __syncthreads();
        sC[t] += a; sO[t] += b2;
        __syncthreads();
    }
    if (t < nb) { blockCnt[t] = sC[t] - c; blockOcc[t] = sO[t] - o; }
    if (t == SCAN_TPB - 1) { totals[0] = sO[t]; totals[1] = sC[t]; }
}

// ---- scan pass 3: add block offsets + emit compact occupied-bin worklist ----
__global__ void scan3_kernel(const uint32_t* __restrict__ binCount,
                             uint32_t* __restrict__ binStart,
                             uint32_t* __restrict__ binSeg,
                             uint32_t* __restrict__ occList,
                             const uint32_t* __restrict__ blockCnt,
                             const uint32_t* __restrict__ blockOcc) {
    int t = threadIdx.x;
    int base = blockIdx.x * BINS_PER_BLOCK + t * BINS_PER_THREAD;
    uint32_t oc = blockCnt[blockIdx.x];
    uint32_t oo = blockOcc[blockIdx.x];
#pragma unroll
    for (int j = 0; j < BINS_PER_THREAD; ++j) {
        uint32_t seg = binSeg[base + j] + oo;
        binStart[base + j] += oc;
        binSeg[base + j] = seg;
        if (binCount[base + j] > 0u) occList[seg] = (uint32_t)(base + j);
    }
}

// ---- scatter: atomic-free; block 0 writes offset_out/n_vox tail ----
__global__ void scatter_kernel(const u32x2* __restrict__ kr,
                               const uint32_t* __restrict__ binStart,
                               uint32_t* __restrict__ pointIdx, int N,
                               const uint32_t* __restrict__ binSeg,
                               const uint32_t* __restrict__ totals,
                               float* __restrict__ out, int B, int C) {
    int i = blockIdx.x * blockDim.x + threadIdx.x;
    if (blockIdx.x == 0 && threadIdx.x <= (unsigned)B) {
        uint32_t nvox = totals[0];
        float* tail = out + (size_t)N * 3 + (size_t)N * C;
        if (threadIdx.x < (unsigned)B) {
            uint32_t v = (threadIdx.x == (unsigned)(B - 1))
                             ? nvox
                             : binSeg[(size_t)(threadIdx.x + 1) * BINS_PER_BATCH];
            tail[threadIdx.x] = (float)v;
        }
        if (threadIdx.x == 0) tail[B] = (float)nvox;
    }
    if (i >= N) return;
    u32x2 k = __builtin_nontemporal_load(&kr[i]);
    pointIdx[binStart[k.x] + k.y] = (uint32_t)i;
}

// ---- per-voxel reduction over COMPACT worklist + fused zero-padding ----
// Wave w < n_vox handles bin occList[w]: seg == w by construction, so
// consecutive waves write consecutive output rows and read contiguous
// pointIdx runs. C==64 fast path: lane = channel, 16-deep unrolled row
// gather (idempotent duplicate-row clamp at the tail); feat loads stay
// cacheable (L3 absorbs ~25% of the random gather). All waves also zero a
// grid-stride chunk of the pad region (overlaps with gather latency).
__global__ __launch_bounds__(256) void reduce_kernel(
        const float* __restrict__ coord, const float* __restrict__ feat,
        const uint32_t* __restrict__ binCount,
        const uint32_t* __restrict__ binStart,
        const uint32_t* __restrict__ occList,
        const uint32_t* __restrict__ pointIdx,
        const uint32_t* __restrict__ totals,
        float* __restrict__ out, int N, int C) {
    int wid = (blockIdx.x << 2) + (threadIdx.x >> 6);
    int lane = threadIdx.x & 63;
    uint32_t nvox = totals[0];
    float* feat_out = out + (size_t)N * 3;

    if ((uint32_t)wid < nvox) {
        int bin = (int)occList[wid];
        uint32_t cnt = binCount[bin];
        uint32_t st = binStart[bin];
        uint32_t seg = (uint32_t)wid;
        float sx = 0.f, sy = 0.f, sz = 0.f;

        if (C == 64) {
            float m = -INFINITY;
            for (uint32_t base = 0; base < cnt; base += 64) {
                uint32_t nchunk = min(64u, cnt - base);
                bool valid = lane < (int)nchunk;
                uint32_t myIdx = valid ? pointIdx[st + base + lane] : 0u;
                if (valid) {
                    const float* cp = coord + (size_t)myIdx * 3;
                    sx += cp[0]; sy += cp[1]; sz += cp[2];
                }
                for (uint32_t p = 0; p < nchunk; p += 16) {
                    float v[16];
#pragma unroll
                    for (int j = 0; j < 16; ++j) {
                        uint32_t pp = min(p + (uint32_t)j, nchunk - 1u);
                        uint32_t idx = __shfl(myIdx, (int)pp);
                        v[j] = feat[(size_t)idx * 64 + lane];
                    }
#pragma unroll
                    for (int s = 1; s < 16; s <<= 1)
#pragma unroll
                        for (int j = 0; j < 16; j += 2 * s)
                            v[j] = fmaxf(v[j], v[j + s]);
                    m = fmaxf(m, v[0]);
                }
            }
            __builtin_nontemporal_store(m, &feat_out[(size_t)seg * 64 + lane]);
        } else {
            for (uint32_t p = lane; p < cnt; p += 64) {
                uint32_t idx = pointIdx[st + p];
                sx += coord[(size_t)idx * 3 + 0];
                sy += coord[(size_t)idx * 3 + 1];
                sz += coord[(size_t)idx * 3 + 2];
            }
            for (int c = lane; c < C; c += 64) {
                float m = -INFINITY;
                for (uint32_t p = 0; p < cnt; ++p) {
                    uint32_t idx = pointIdx[st + p];
                    m = fmaxf(m, feat[(size_t)idx * C + c]);
                }
                feat_out[(size_t)seg * C + c] = m;
            }
        }

        for (int off = 32; off > 0; off >>= 1) {
            sx += __shfl_xor(sx, off);
            sy += __shfl_xor(sy, off);
            sz += __shfl_xor(sz, off);
        }
        if (lane == 0) {
            float inv = 1.0f / (float)cnt;
            out[(size_t)seg * 3 + 0] = sx * inv;
            out[(size_t)seg * 3 + 1] = sy * inv;
            out[(size_t)seg * 3 + 2] = sz * inv;
        }
    }

    // fused division-free grid-stride zero-pad of rows >= n_vox
    uint32_t tid = (uint32_t)blockIdx.x * blockDim.x + threadIdx.x;
    uint32_t nthreads = (uint32_t)gridDim.x * blockDim.x;
    uint32_t rows = (uint32_t)N - nvox;
    if ((C & 3) == 0) {
        f32x4 z4 = {0.f, 0.f, 0.f, 0.f};
        uint32_t quadsTotal = rows * (uint32_t)(C >> 2);
        f32x4* padBase = (f32x4*)(feat_out + (size_t)nvox * C);
        for (uint32_t q = tid; q < quadsTotal; q += nthreads)
            __builtin_nontemporal_store(z4, &padBase[q]);
    } else {
        uint32_t eTotal = rows * (uint32_t)C;
        float* padBase = feat_out + (size_t)nvox * C;
        for (uint32_t e = tid; e < eTotal; e += nthreads)
            __builtin_nontemporal_store(0.f, &padBase[e]);
    }
    {
        uint32_t cTotal = rows * 3u;
        float* cBase = out + (size_t)nvox * 3;
        for (uint32_t e = tid; e < cTotal; e += nthreads)
            __builtin_nontemporal_store(0.f, &cBase[e]);
    }
}

extern "C" void kernel_launch(void* const* d_in, const int* in_sizes, int n_in,
                              void* d_out, int out_size, void* d_ws, size_t ws_size,
                              hipStream_t stream) {
    const float* coord = (const float*)d_in[0];
    const float* feat  = (const float*)d_in[1];
    const int*   offs  = (const int*)d_in[2];
    float* out = (float*)d_out;

    int N = in_sizes[0] / 3;
    int C = in_sizes[1] / N;
    int B = in_sizes[2];
    int NBINS = B * BINS_PER_BATCH;          // 131072 for B=4
    int NB1 = NBINS / BINS_PER_BLOCK;        // 128

    // workspace layout
    uint8_t* w = (uint8_t*)d_ws;
    uint32_t* binCount = (uint32_t*)w;              w += (size_t)NBINS * 4;
    uint32_t* binStart = (uint32_t*)w;              w += (size_t)NBINS * 4;
    uint32_t* binSeg   = (uint32_t*)w;              w += (size_t)NBINS * 4;
    uint32_t* occList  = (uint32_t*)w;              w += (size_t)NBINS * 4;
    uint32_t* blockCnt = (uint32_t*)w;              w += (size_t)NB1 * 4;
    uint32_t* blockOcc = (uint32_t*)w;              w += (size_t)NB1 * 4;
    uint32_t* totals   = (uint32_t*)w;              w += 2 * 4;
    int*      startBits= (int*)w;                   w += (size_t)3 * B * 4 + 8;
    u32x2*    kr       = (u32x2*)w;                 w += (size_t)N * 8;
    uint32_t* pointIdx = (uint32_t*)w;              /* w += N*4 */

    int ptBlocks = (N + 255) / 256;
    int kcBlocks = (N + 256 * KC_PPT - 1) / (256 * KC_PPT);

    init_kernel<<<512, 256, 0, stream>>>(binCount, NBINS, startBits, B);
    if (B <= 4) {
        batch_min4_kernel<<<1024, 256, 0, stream>>>(coord, offs, B, N, startBits);
        keys_count4_kernel<<<kcBlocks, 256, 0, stream>>>(coord, offs, startBits,
                                                         B, N, kr, binCount);
    } else {
        batch_min_generic_kernel<<<ptBlocks, 256, 0, stream>>>(coord, offs, B, N,
                                                               startBits);
        keys_count_generic_kernel<<<ptBlocks, 256, 0, stream>>>(coord, offs,
                                                                startBits, B, N,
                                                                kr, binCount);
    }
    scan1_kernel<<<NB1, SCAN_TPB, 0, stream>>>(binCount, binStart, binSeg,
                                               blockCnt, blockOcc);
    scan2_kernel<<<1, SCAN_TPB, 0, stream>>>(blockCnt, blockOcc, totals, NB1);
    scan3_kernel<<<NB1, SCAN_TPB, 0, stream>>>(binCount, binStart, binSeg,
                                               occList, blockCnt, blockOcc);
    scatter_kernel<<<ptBlocks, 256, 0, stream>>>(kr, binStart, pointIdx, N,
                                                 binSeg, totals, out, B, C);
    reduce_kernel<<<NBINS / 4, 256, 0, stream>>>(coord, feat, binCount, binStart,
                                                 occList, pointIdx, totals, out,
                                                 N, C);
}